// Round 2
// baseline (946.319 us; speedup 1.0000x reference)
//
#include <hip/hip_runtime.h>
#include <hip/hip_bf16.h>

// GCN 2-layer encoder, N=100000 nodes, C=128 features, E=1.6M edges.
// out[N,256] = concat(relu(gcn(x,W1,b1)), relu(gcn(relu1,W2,b2)))
// gcn: h=XW; agg[d] = sum_{(s,d) in A+I} h[s]*dinv[s]*dinv[d]; +b
// dinv = rsqrt(1 + in_degree(dst))

#define FEAT 128

// ---------------- CSR build ----------------

__global__ void count_edges_kernel(const int* __restrict__ dst, int E,
                                   int* __restrict__ cnt) {
    int e = blockIdx.x * 256 + threadIdx.x;
    if (e < E) atomicAdd(&cnt[dst[e]], 1);
}

__global__ void compute_dinv_kernel(const int* __restrict__ cnt,
                                    float* __restrict__ dinv, int N) {
    int i = blockIdx.x * 256 + threadIdx.x;
    if (i < N) dinv[i] = rsqrtf((float)(cnt[i] + 1));  // +1 self loop
}

// Single-block exclusive scan of cnt[0..N) into rowptr[0..N].
__global__ __launch_bounds__(1024) void scan_kernel(const int* __restrict__ cnt,
                                                    int* __restrict__ rowptr, int N) {
    __shared__ int sums[1024];
    int tid = threadIdx.x;
    int chunk = (N + 1023) / 1024;
    int start = tid * chunk;
    int end = start + chunk; if (end > N) end = N;
    int s = 0;
    for (int i = start; i < end && start < N; ++i) s += cnt[i];
    sums[tid] = (start < N) ? s : 0;
    __syncthreads();
    // Hillis-Steele inclusive scan
    for (int off = 1; off < 1024; off <<= 1) {
        int v = sums[tid];
        int add = (tid >= off) ? sums[tid - off] : 0;
        __syncthreads();
        sums[tid] = v + add;
        __syncthreads();
    }
    int run = (tid == 0) ? 0 : sums[tid - 1];
    if (tid == 0) rowptr[0] = 0;
    if (start < N) {
        for (int i = start; i < end; ++i) { run += cnt[i]; rowptr[i + 1] = run; }
    }
}

__global__ void fill_csr_kernel(const int* __restrict__ src, const int* __restrict__ dst,
                                int E, const int* __restrict__ rowptr,
                                int* __restrict__ cur, int* __restrict__ csr_src) {
    int e = blockIdx.x * 256 + threadIdx.x;
    if (e < E) {
        int d = dst[e];
        int pos = atomicAdd(&cur[d], 1);
        csr_src[rowptr[d] + pos] = src[e];
    }
}

// ---------------- fp32 GEMM: H[M,128] = X[M,ldx(0:128)] @ W[128,128] ----------------
// 64 rows x 128 cols per block, 256 threads, x-tile staged in LDS.

__global__ __launch_bounds__(256) void gemm_f32_kernel(const float* __restrict__ X, int ldx,
                                                       const float* __restrict__ W,
                                                       float* __restrict__ H, int M) {
    __shared__ float xs[64][132];  // +4 pad (2-way LDS alias only -> free)
    int tid = threadIdx.x;
    int row0 = blockIdx.x * 64;

    // load 64x128 x-tile: 2048 float4, 8 per thread
#pragma unroll
    for (int i = 0; i < 8; ++i) {
        int idx = tid + i * 256;
        int r = idx >> 5, c4 = (idx & 31) * 4;
        int gr = row0 + r;
        float4 v = make_float4(0.f, 0.f, 0.f, 0.f);
        if (gr < M) v = *(const float4*)(X + (size_t)gr * ldx + c4);
        xs[r][c4 + 0] = v.x; xs[r][c4 + 1] = v.y;
        xs[r][c4 + 2] = v.z; xs[r][c4 + 3] = v.w;
    }
    __syncthreads();

    int tx = tid & 15;   // col group: cols tx*8 .. +8
    int ty = tid >> 4;   // row group: rows ty*4 .. +4
    float acc[4][8];
#pragma unroll
    for (int i = 0; i < 4; ++i)
#pragma unroll
        for (int j = 0; j < 8; ++j) acc[i][j] = 0.f;

    for (int k = 0; k < 128; ++k) {
        float xv[4];
#pragma unroll
        for (int i = 0; i < 4; ++i) xv[i] = xs[ty * 4 + i][k];
        const float4* wr = (const float4*)(W + k * 128 + tx * 8);
        float4 w0 = wr[0], w1 = wr[1];
        float wv[8] = {w0.x, w0.y, w0.z, w0.w, w1.x, w1.y, w1.z, w1.w};
#pragma unroll
        for (int i = 0; i < 4; ++i)
#pragma unroll
            for (int j = 0; j < 8; ++j) acc[i][j] = fmaf(xv[i], wv[j], acc[i][j]);
    }

#pragma unroll
    for (int i = 0; i < 4; ++i) {
        int gr = row0 + ty * 4 + i;
        if (gr < M) {
            float4* o = (float4*)(H + (size_t)gr * FEAT + tx * 8);
            o[0] = make_float4(acc[i][0], acc[i][1], acc[i][2], acc[i][3]);
            o[1] = make_float4(acc[i][4], acc[i][5], acc[i][6], acc[i][7]);
        }
    }
}

// ---------------- aggregation: one wave per dst node ----------------
// out[node, coloff + f] = relu( dinv[node] * (h[node,f]*dinv[node]
//                         + sum_e h[src_e,f]*dinv[src_e]) + bias[f] )

__global__ __launch_bounds__(256) void aggregate_kernel(const float* __restrict__ H,
    const float* __restrict__ dinv, const int* __restrict__ rowptr,
    const int* __restrict__ csr_src, const float* __restrict__ bias,
    float* __restrict__ out, int ldo, int coloff, int N) {
    int node = blockIdx.x * 4 + (threadIdx.x >> 6);
    if (node >= N) return;
    int lane = threadIdx.x & 63;

    float di = dinv[node];
    float2 acc = ((const float2*)(H + (size_t)node * FEAT))[lane];
    acc.x *= di; acc.y *= di;  // self-loop: h[d]*dinv[d] (outer di applied later)

    int e0 = rowptr[node], e1 = rowptr[node + 1];
    for (int e = e0; e < e1; ++e) {
        int s = csr_src[e];
        float ds = dinv[s];
        float2 hv = ((const float2*)(H + (size_t)s * FEAT))[lane];
        acc.x = fmaf(hv.x, ds, acc.x);
        acc.y = fmaf(hv.y, ds, acc.y);
    }
    acc.x *= di; acc.y *= di;
    acc.x += bias[lane * 2];
    acc.y += bias[lane * 2 + 1];
    acc.x = fmaxf(acc.x, 0.f);
    acc.y = fmaxf(acc.y, 0.f);
    ((float2*)(out + (size_t)node * ldo + coloff))[lane] = acc;
}

// ---------------- launch ----------------

extern "C" void kernel_launch(void* const* d_in, const int* in_sizes, int n_in,
                              void* d_out, int out_size, void* d_ws, size_t ws_size,
                              hipStream_t stream) {
    const float* x  = (const float*)d_in[0];
    const int*   ei = (const int*)d_in[1];   // int32 on device (JAX x64 disabled)
    const float* W1 = (const float*)d_in[2];
    const float* b1 = (const float*)d_in[3];
    const float* W2 = (const float*)d_in[4];
    const float* b2 = (const float*)d_in[5];
    float* out = (float*)d_out;

    const int N = in_sizes[0] / FEAT;   // 100000
    const int E = in_sizes[1] / 2;      // 1600000
    const int* srcs = ei;
    const int* dsts = ei + E;

    // workspace layout (all 16B-aligned chunks)
    char* w = (char*)d_ws;
    float* h      = (float*)w; w += (size_t)N * FEAT * sizeof(float);  // 51.2 MB
    float* dinv   = (float*)w; w += (size_t)N * sizeof(float);
    int*   cnt    = (int*)w;   w += (size_t)N * sizeof(int);
    int*   cur    = (int*)w;   w += (size_t)N * sizeof(int);
    int*   rowptr = (int*)w;   w += (size_t)(N + 4) * sizeof(int);
    int*   csr    = (int*)w;   w += (size_t)E * sizeof(int);

    hipMemsetAsync(cnt, 0, (size_t)N * sizeof(int), stream);
    hipMemsetAsync(cur, 0, (size_t)N * sizeof(int), stream);

    int eg = (E + 255) / 256;
    int ng = (N + 255) / 256;
    count_edges_kernel<<<eg, 256, 0, stream>>>(dsts, E, cnt);
    compute_dinv_kernel<<<ng, 256, 0, stream>>>(cnt, dinv, N);
    scan_kernel<<<1, 1024, 0, stream>>>(cnt, rowptr, N);
    fill_csr_kernel<<<eg, 256, 0, stream>>>(srcs, dsts, E, rowptr, cur, csr);

    int gg = (N + 63) / 64;
    int ag = (N + 3) / 4;
    // layer 1
    gemm_f32_kernel<<<gg, 256, 0, stream>>>(x, FEAT, W1, h, N);
    aggregate_kernel<<<ag, 256, 0, stream>>>(h, dinv, rowptr, csr, b1, out, 2 * FEAT, 0, N);
    // layer 2 (input = out cols 0..127, row stride 256)
    gemm_f32_kernel<<<gg, 256, 0, stream>>>(out, 2 * FEAT, W2, h, N);
    aggregate_kernel<<<ag, 256, 0, stream>>>(h, dinv, rowptr, csr, b2, out, 2 * FEAT, FEAT, N);
}

// Round 3
// 768.127 us; speedup vs baseline: 1.2320x; 1.2320x over previous
//
#include <hip/hip_runtime.h>
#include <hip/hip_bf16.h>

// GCN 2-layer encoder, N=100000 nodes, C=128 features, E=1.6M edges.
// out[N,256] = concat(relu(gcn(x,W1,b1)), relu(gcn(relu1,W2,b2)))
// gcn: h=XW; agg[d] = sum_{(s,d) in A+I} h[s]*dinv[s]*dinv[d]; +b
// dinv = rsqrt(1 + in_degree(dst))
//
// R1 -> R2: single-block scan (190us, Occupancy 0.17%) replaced with
// 3-phase multi-block scan; dinv fused into phase 1.

#define FEAT 128

// ---------------- CSR build ----------------

__global__ void count_edges_kernel(const int* __restrict__ dst, int E,
                                   int* __restrict__ cnt) {
    int e = blockIdx.x * 256 + threadIdx.x;
    if (e < E) atomicAdd(&cnt[dst[e]], 1);
}

// Phase 1: per-block (1024-wide) inclusive scan of cnt; also emits dinv.
__global__ __launch_bounds__(1024) void scan_block_kernel(
    const int* __restrict__ cnt, int* __restrict__ incl,
    int* __restrict__ bsum, float* __restrict__ dinv, int N) {
    __shared__ int s[1024];
    int tid = threadIdx.x;
    int i = blockIdx.x * 1024 + tid;
    int v = (i < N) ? cnt[i] : 0;
    if (i < N) dinv[i] = rsqrtf((float)(v + 1));  // +1 self loop
    s[tid] = v;
    __syncthreads();
    for (int off = 1; off < 1024; off <<= 1) {
        int add = (tid >= off) ? s[tid - off] : 0;
        __syncthreads();
        s[tid] += add;
        __syncthreads();
    }
    if (i < N) incl[i] = s[tid];
    if (tid == 1023) bsum[blockIdx.x] = s[1023];
}

// Phase 2: exclusive scan of block sums (NB <= 128), single tiny block.
__global__ __launch_bounds__(128) void scan_bsum_kernel(int* __restrict__ bsum, int NB) {
    __shared__ int s[128];
    int tid = threadIdx.x;
    int v = (tid < NB) ? bsum[tid] : 0;
    s[tid] = v;
    __syncthreads();
    for (int off = 1; off < 128; off <<= 1) {
        int add = (tid >= off) ? s[tid - off] : 0;
        __syncthreads();
        s[tid] += add;
        __syncthreads();
    }
    if (tid < NB) bsum[tid] = s[tid] - v;  // exclusive
}

// Phase 3: rowptr[i+1] = incl[i] + block_offset; rowptr[0] = 0.
__global__ void scan_finalize_kernel(const int* __restrict__ incl,
                                     const int* __restrict__ bsum,
                                     int* __restrict__ rowptr, int N) {
    int i = blockIdx.x * 256 + threadIdx.x;
    if (i < N) rowptr[i + 1] = incl[i] + bsum[i >> 10];
    if (i == 0) rowptr[0] = 0;
}

__global__ void fill_csr_kernel(const int* __restrict__ src, const int* __restrict__ dst,
                                int E, const int* __restrict__ rowptr,
                                int* __restrict__ cur, int* __restrict__ csr_src) {
    int e = blockIdx.x * 256 + threadIdx.x;
    if (e < E) {
        int d = dst[e];
        int pos = atomicAdd(&cur[d], 1);
        csr_src[rowptr[d] + pos] = src[e];
    }
}

// ---------------- fp32 GEMM: H[M,128] = X[M,ldx(0:128)] @ W[128,128] ----------------
// 64 rows x 128 cols per block, 256 threads, x-tile staged in LDS.

__global__ __launch_bounds__(256) void gemm_f32_kernel(const float* __restrict__ X, int ldx,
                                                       const float* __restrict__ W,
                                                       float* __restrict__ H, int M) {
    __shared__ float xs[64][132];  // +4 pad
    int tid = threadIdx.x;
    int row0 = blockIdx.x * 64;

#pragma unroll
    for (int i = 0; i < 8; ++i) {
        int idx = tid + i * 256;
        int r = idx >> 5, c4 = (idx & 31) * 4;
        int gr = row0 + r;
        float4 v = make_float4(0.f, 0.f, 0.f, 0.f);
        if (gr < M) v = *(const float4*)(X + (size_t)gr * ldx + c4);
        xs[r][c4 + 0] = v.x; xs[r][c4 + 1] = v.y;
        xs[r][c4 + 2] = v.z; xs[r][c4 + 3] = v.w;
    }
    __syncthreads();

    int tx = tid & 15;   // col group: cols tx*8 .. +8
    int ty = tid >> 4;   // row group: rows ty*4 .. +4
    float acc[4][8];
#pragma unroll
    for (int i = 0; i < 4; ++i)
#pragma unroll
        for (int j = 0; j < 8; ++j) acc[i][j] = 0.f;

    for (int k = 0; k < 128; ++k) {
        float xv[4];
#pragma unroll
        for (int i = 0; i < 4; ++i) xv[i] = xs[ty * 4 + i][k];
        const float4* wr = (const float4*)(W + k * 128 + tx * 8);
        float4 w0 = wr[0], w1 = wr[1];
        float wv[8] = {w0.x, w0.y, w0.z, w0.w, w1.x, w1.y, w1.z, w1.w};
#pragma unroll
        for (int i = 0; i < 4; ++i)
#pragma unroll
            for (int j = 0; j < 8; ++j) acc[i][j] = fmaf(xv[i], wv[j], acc[i][j]);
    }

#pragma unroll
    for (int i = 0; i < 4; ++i) {
        int gr = row0 + ty * 4 + i;
        if (gr < M) {
            float4* o = (float4*)(H + (size_t)gr * FEAT + tx * 8);
            o[0] = make_float4(acc[i][0], acc[i][1], acc[i][2], acc[i][3]);
            o[1] = make_float4(acc[i][4], acc[i][5], acc[i][6], acc[i][7]);
        }
    }
}

// ---------------- aggregation: one wave per dst node ----------------

__global__ __launch_bounds__(256) void aggregate_kernel(const float* __restrict__ H,
    const float* __restrict__ dinv, const int* __restrict__ rowptr,
    const int* __restrict__ csr_src, const float* __restrict__ bias,
    float* __restrict__ out, int ldo, int coloff, int N) {
    int node = blockIdx.x * 4 + (threadIdx.x >> 6);
    if (node >= N) return;
    int lane = threadIdx.x & 63;

    float di = dinv[node];
    float2 acc = ((const float2*)(H + (size_t)node * FEAT))[lane];
    acc.x *= di; acc.y *= di;  // self-loop (outer di applied later)

    int e0 = rowptr[node], e1 = rowptr[node + 1];
    for (int e = e0; e < e1; ++e) {
        int s = csr_src[e];
        float ds = dinv[s];
        float2 hv = ((const float2*)(H + (size_t)s * FEAT))[lane];
        acc.x = fmaf(hv.x, ds, acc.x);
        acc.y = fmaf(hv.y, ds, acc.y);
    }
    acc.x *= di; acc.y *= di;
    acc.x += bias[lane * 2];
    acc.y += bias[lane * 2 + 1];
    acc.x = fmaxf(acc.x, 0.f);
    acc.y = fmaxf(acc.y, 0.f);
    ((float2*)(out + (size_t)node * ldo + coloff))[lane] = acc;
}

// ---------------- launch ----------------

extern "C" void kernel_launch(void* const* d_in, const int* in_sizes, int n_in,
                              void* d_out, int out_size, void* d_ws, size_t ws_size,
                              hipStream_t stream) {
    const float* x  = (const float*)d_in[0];
    const int*   ei = (const int*)d_in[1];   // int32 on device (JAX x64 disabled)
    const float* W1 = (const float*)d_in[2];
    const float* b1 = (const float*)d_in[3];
    const float* W2 = (const float*)d_in[4];
    const float* b2 = (const float*)d_in[5];
    float* out = (float*)d_out;

    const int N = in_sizes[0] / FEAT;   // 100000
    const int E = in_sizes[1] / 2;      // 1600000
    const int* srcs = ei;
    const int* dsts = ei + E;

    const int NB = (N + 1023) / 1024;   // scan blocks (98 <= 128)

    // workspace layout (16B-aligned chunks)
    char* w = (char*)d_ws;
    float* h      = (float*)w; w += (size_t)N * FEAT * sizeof(float);  // 51.2 MB
    float* dinv   = (float*)w; w += (size_t)N * sizeof(float);
    int*   cnt    = (int*)w;   w += (size_t)N * sizeof(int);
    int*   cur    = (int*)w;   w += (size_t)N * sizeof(int);
    int*   rowptr = (int*)w;   w += (size_t)(N + 4) * sizeof(int);
    int*   csr    = (int*)w;   w += (size_t)E * sizeof(int);
    int*   incl   = (int*)w;   w += (size_t)N * sizeof(int);
    int*   bsum   = (int*)w;   w += 128 * sizeof(int);

    hipMemsetAsync(cnt, 0, (size_t)N * sizeof(int), stream);
    hipMemsetAsync(cur, 0, (size_t)N * sizeof(int), stream);

    int eg = (E + 255) / 256;
    int ng = (N + 255) / 256;
    count_edges_kernel<<<eg, 256, 0, stream>>>(dsts, E, cnt);
    scan_block_kernel<<<NB, 1024, 0, stream>>>(cnt, incl, bsum, dinv, N);
    scan_bsum_kernel<<<1, 128, 0, stream>>>(bsum, NB);
    scan_finalize_kernel<<<ng, 256, 0, stream>>>(incl, bsum, rowptr, N);
    fill_csr_kernel<<<eg, 256, 0, stream>>>(srcs, dsts, E, rowptr, cur, csr);

    int gg = (N + 63) / 64;
    int ag = (N + 3) / 4;
    // layer 1
    gemm_f32_kernel<<<gg, 256, 0, stream>>>(x, FEAT, W1, h, N);
    aggregate_kernel<<<ag, 256, 0, stream>>>(h, dinv, rowptr, csr, b1, out, 2 * FEAT, 0, N);
    // layer 2 (input = out cols 0..127, row stride 256)
    gemm_f32_kernel<<<gg, 256, 0, stream>>>(out, 2 * FEAT, W2, h, N);
    aggregate_kernel<<<ag, 256, 0, stream>>>(h, dinv, rowptr, csr, b2, out, 2 * FEAT, FEAT, N);
}

// Round 4
// 571.432 us; speedup vs baseline: 1.6561x; 1.3442x over previous
//
#include <hip/hip_runtime.h>
#include <hip/hip_bf16.h>

// GCN 2-layer encoder, N=100000 nodes, C=128 features, E=1.6M edges.
// out[N,256] = concat(relu(gcn(x,W1,b1)), relu(gcn(relu1,W2,b2)))
// gcn: h=XW; agg[d] = sum_{(s,d) in A+I} h[s]*dinv[s]*dinv[d]; +b
// dinv = rsqrt(1 + in_degree(dst))
//
// R1 -> R2: multi-block scan (was 190us single-block, 0.17% occupancy).
// R2 -> R3: h stored as packed bf16 (gather rows 512B -> 256B; agg was
//           476MB @ 2.7TB/s) + edge loop batched x4 for MLP.

#define FEAT 128
#define HW 64   // packed words per h row (2 bf16 per uint)

static __device__ inline unsigned pack_bf16(float a, float b) {
    unsigned ua = __float_as_uint(a), ub = __float_as_uint(b);
    ua = (ua + 0x7fff + ((ua >> 16) & 1)) >> 16;   // RNE
    ub = (ub + 0x7fff + ((ub >> 16) & 1)) >> 16;
    return (ua & 0xffffu) | (ub << 16);
}

// ---------------- CSR build ----------------

__global__ void count_edges_kernel(const int* __restrict__ dst, int E,
                                   int* __restrict__ cnt) {
    int e = blockIdx.x * 256 + threadIdx.x;
    if (e < E) atomicAdd(&cnt[dst[e]], 1);
}

// Phase 1: per-block (1024-wide) inclusive scan of cnt; also emits dinv.
__global__ __launch_bounds__(1024) void scan_block_kernel(
    const int* __restrict__ cnt, int* __restrict__ incl,
    int* __restrict__ bsum, float* __restrict__ dinv, int N) {
    __shared__ int s[1024];
    int tid = threadIdx.x;
    int i = blockIdx.x * 1024 + tid;
    int v = (i < N) ? cnt[i] : 0;
    if (i < N) dinv[i] = rsqrtf((float)(v + 1));  // +1 self loop
    s[tid] = v;
    __syncthreads();
    for (int off = 1; off < 1024; off <<= 1) {
        int add = (tid >= off) ? s[tid - off] : 0;
        __syncthreads();
        s[tid] += add;
        __syncthreads();
    }
    if (i < N) incl[i] = s[tid];
    if (tid == 1023) bsum[blockIdx.x] = s[1023];
}

// Phase 2: exclusive scan of block sums (NB <= 128), single tiny block.
__global__ __launch_bounds__(128) void scan_bsum_kernel(int* __restrict__ bsum, int NB) {
    __shared__ int s[128];
    int tid = threadIdx.x;
    int v = (tid < NB) ? bsum[tid] : 0;
    s[tid] = v;
    __syncthreads();
    for (int off = 1; off < 128; off <<= 1) {
        int add = (tid >= off) ? s[tid - off] : 0;
        __syncthreads();
        s[tid] += add;
        __syncthreads();
    }
    if (tid < NB) bsum[tid] = s[tid] - v;  // exclusive
}

// Phase 3: rowptr[i+1] = incl[i] + block_offset; rowptr[0] = 0.
__global__ void scan_finalize_kernel(const int* __restrict__ incl,
                                     const int* __restrict__ bsum,
                                     int* __restrict__ rowptr, int N) {
    int i = blockIdx.x * 256 + threadIdx.x;
    if (i < N) rowptr[i + 1] = incl[i] + bsum[i >> 10];
    if (i == 0) rowptr[0] = 0;
}

__global__ void fill_csr_kernel(const int* __restrict__ src, const int* __restrict__ dst,
                                int E, const int* __restrict__ rowptr,
                                int* __restrict__ cur, int* __restrict__ csr_src) {
    int e = blockIdx.x * 256 + threadIdx.x;
    if (e < E) {
        int d = dst[e];
        int pos = atomicAdd(&cur[d], 1);
        csr_src[rowptr[d] + pos] = src[e];
    }
}

// ---------------- fp32 GEMM -> packed bf16 H ----------------
// H[M, 64 words] = pack_bf16( X[M, ldx(0:128)] @ W[128,128] )
// 64 rows x 128 cols per block, 256 threads, x-tile staged in LDS.

__global__ __launch_bounds__(256) void gemm_f32_kernel(const float* __restrict__ X, int ldx,
                                                       const float* __restrict__ W,
                                                       unsigned* __restrict__ H, int M) {
    __shared__ float xs[64][132];  // +4 pad
    int tid = threadIdx.x;
    int row0 = blockIdx.x * 64;

#pragma unroll
    for (int i = 0; i < 8; ++i) {
        int idx = tid + i * 256;
        int r = idx >> 5, c4 = (idx & 31) * 4;
        int gr = row0 + r;
        float4 v = make_float4(0.f, 0.f, 0.f, 0.f);
        if (gr < M) v = *(const float4*)(X + (size_t)gr * ldx + c4);
        xs[r][c4 + 0] = v.x; xs[r][c4 + 1] = v.y;
        xs[r][c4 + 2] = v.z; xs[r][c4 + 3] = v.w;
    }
    __syncthreads();

    int tx = tid & 15;   // col group: cols tx*8 .. +8
    int ty = tid >> 4;   // row group: rows ty*4 .. +4
    float acc[4][8];
#pragma unroll
    for (int i = 0; i < 4; ++i)
#pragma unroll
        for (int j = 0; j < 8; ++j) acc[i][j] = 0.f;

    for (int k = 0; k < 128; ++k) {
        float xv[4];
#pragma unroll
        for (int i = 0; i < 4; ++i) xv[i] = xs[ty * 4 + i][k];
        const float4* wr = (const float4*)(W + k * 128 + tx * 8);
        float4 w0 = wr[0], w1 = wr[1];
        float wv[8] = {w0.x, w0.y, w0.z, w0.w, w1.x, w1.y, w1.z, w1.w};
#pragma unroll
        for (int i = 0; i < 4; ++i)
#pragma unroll
            for (int j = 0; j < 8; ++j) acc[i][j] = fmaf(xv[i], wv[j], acc[i][j]);
    }

#pragma unroll
    for (int i = 0; i < 4; ++i) {
        int gr = row0 + ty * 4 + i;
        if (gr < M) {
            uint4 pv;
            pv.x = pack_bf16(acc[i][0], acc[i][1]);
            pv.y = pack_bf16(acc[i][2], acc[i][3]);
            pv.z = pack_bf16(acc[i][4], acc[i][5]);
            pv.w = pack_bf16(acc[i][6], acc[i][7]);
            *(uint4*)(H + (size_t)gr * HW + tx * 4) = pv;
        }
    }
}

// ---------------- aggregation: one wave per dst node ----------------
// Gathers packed-bf16 rows (256B/row), accumulates fp32.

__global__ __launch_bounds__(256) void aggregate_kernel(const unsigned* __restrict__ H,
    const float* __restrict__ dinv, const int* __restrict__ rowptr,
    const int* __restrict__ csr_src, const float* __restrict__ bias,
    float* __restrict__ out, int ldo, int coloff, int N) {
    int node = blockIdx.x * 4 + (threadIdx.x >> 6);
    if (node >= N) return;
    int lane = threadIdx.x & 63;

    float di = dinv[node];
    float ax, ay;
    {
        unsigned v = H[(size_t)node * HW + lane];
        ax = __uint_as_float(v << 16) * di;            // feat 2*lane
        ay = __uint_as_float(v & 0xffff0000u) * di;    // feat 2*lane+1
    }

    int e0 = rowptr[node], e1 = rowptr[node + 1];
    int e = e0;
    // 4-wide batches: independent index loads, then independent row gathers
    for (; e + 3 < e1; e += 4) {
        int s0 = csr_src[e + 0], s1 = csr_src[e + 1];
        int s2 = csr_src[e + 2], s3 = csr_src[e + 3];
        float w0 = dinv[s0], w1 = dinv[s1], w2 = dinv[s2], w3 = dinv[s3];
        unsigned v0 = H[(size_t)s0 * HW + lane];
        unsigned v1 = H[(size_t)s1 * HW + lane];
        unsigned v2 = H[(size_t)s2 * HW + lane];
        unsigned v3 = H[(size_t)s3 * HW + lane];
        ax = fmaf(__uint_as_float(v0 << 16), w0, ax);
        ay = fmaf(__uint_as_float(v0 & 0xffff0000u), w0, ay);
        ax = fmaf(__uint_as_float(v1 << 16), w1, ax);
        ay = fmaf(__uint_as_float(v1 & 0xffff0000u), w1, ay);
        ax = fmaf(__uint_as_float(v2 << 16), w2, ax);
        ay = fmaf(__uint_as_float(v2 & 0xffff0000u), w2, ay);
        ax = fmaf(__uint_as_float(v3 << 16), w3, ax);
        ay = fmaf(__uint_as_float(v3 & 0xffff0000u), w3, ay);
    }
    for (; e < e1; ++e) {
        int s = csr_src[e];
        float ws = dinv[s];
        unsigned v = H[(size_t)s * HW + lane];
        ax = fmaf(__uint_as_float(v << 16), ws, ax);
        ay = fmaf(__uint_as_float(v & 0xffff0000u), ws, ay);
    }

    ax = ax * di + bias[lane * 2];
    ay = ay * di + bias[lane * 2 + 1];
    ax = fmaxf(ax, 0.f);
    ay = fmaxf(ay, 0.f);
    ((float2*)(out + (size_t)node * ldo + coloff))[lane] = make_float2(ax, ay);
}

// ---------------- launch ----------------

extern "C" void kernel_launch(void* const* d_in, const int* in_sizes, int n_in,
                              void* d_out, int out_size, void* d_ws, size_t ws_size,
                              hipStream_t stream) {
    const float* x  = (const float*)d_in[0];
    const int*   ei = (const int*)d_in[1];   // int32 on device (JAX x64 disabled)
    const float* W1 = (const float*)d_in[2];
    const float* b1 = (const float*)d_in[3];
    const float* W2 = (const float*)d_in[4];
    const float* b2 = (const float*)d_in[5];
    float* out = (float*)d_out;

    const int N = in_sizes[0] / FEAT;   // 100000
    const int E = in_sizes[1] / 2;      // 1600000
    const int* srcs = ei;
    const int* dsts = ei + E;

    const int NB = (N + 1023) / 1024;   // scan blocks (98 <= 128)

    // workspace layout (16B-aligned chunks)
    char* w = (char*)d_ws;
    unsigned* hb  = (unsigned*)w; w += (size_t)N * HW * sizeof(unsigned);  // 25.6 MB
    float* dinv   = (float*)w; w += (size_t)N * sizeof(float);
    int*   cnt    = (int*)w;   w += (size_t)N * sizeof(int);
    int*   cur    = (int*)w;   w += (size_t)N * sizeof(int);
    int*   rowptr = (int*)w;   w += (size_t)(N + 4) * sizeof(int);
    int*   csr    = (int*)w;   w += (size_t)E * sizeof(int);
    int*   incl   = (int*)w;   w += (size_t)N * sizeof(int);
    int*   bsum   = (int*)w;   w += 128 * sizeof(int);

    hipMemsetAsync(cnt, 0, (size_t)N * sizeof(int), stream);
    hipMemsetAsync(cur, 0, (size_t)N * sizeof(int), stream);

    int eg = (E + 255) / 256;
    int ng = (N + 255) / 256;
    count_edges_kernel<<<eg, 256, 0, stream>>>(dsts, E, cnt);
    scan_block_kernel<<<NB, 1024, 0, stream>>>(cnt, incl, bsum, dinv, N);
    scan_bsum_kernel<<<1, 128, 0, stream>>>(bsum, NB);
    scan_finalize_kernel<<<ng, 256, 0, stream>>>(incl, bsum, rowptr, N);
    fill_csr_kernel<<<eg, 256, 0, stream>>>(srcs, dsts, E, rowptr, cur, csr);

    int gg = (N + 63) / 64;
    int ag = (N + 3) / 4;
    // layer 1
    gemm_f32_kernel<<<gg, 256, 0, stream>>>(x, FEAT, W1, hb, N);
    aggregate_kernel<<<ag, 256, 0, stream>>>(hb, dinv, rowptr, csr, b1, out, 2 * FEAT, 0, N);
    // layer 2 (input = out cols 0..127, row stride 256)
    gemm_f32_kernel<<<gg, 256, 0, stream>>>(out, 2 * FEAT, W2, hb, N);
    aggregate_kernel<<<ag, 256, 0, stream>>>(hb, dinv, rowptr, csr, b2, out, 2 * FEAT, FEAT, N);
}

// Round 6
// 496.129 us; speedup vs baseline: 1.9074x; 1.1518x over previous
//
#include <hip/hip_runtime.h>
#include <hip/hip_bf16.h>

// GCN 2-layer encoder, N=100000 nodes, C=128 features, E=1.6M edges.
// out[N,256] = concat(relu(gcn(x,W1,b1)), relu(gcn(relu1,W2,b2)))
// gcn: h=XW; agg[d] = sum_{(s,d) in A+I} h[s]*dinv[s]*dinv[d]; +b
// dinv = rsqrt(1 + in_degree(dst))
//
// R1 -> R2: multi-block scan (was 190us single-block, 0.17% occupancy).
// R2 -> R3: h stored packed bf16 (gather 512B->256B rows) + edge loop x4.
// R3 -> R4: GEMM moved to MFMA with split-bf16 (hi/lo) 3-term product:
//           fp32-like accuracy at matrix-pipe rate (was 85us @ 39% VALU,
//           0% MFMA, vector-fp32 floor is ~21us). W pre-swizzled into
//           B-fragment order; X tile LDS-staged hi/lo with XOR swizzle.
//           H word layout permuted: word j*16+c holds feats (32j+c, +16).

#define FEAT 128
#define HW 64   // packed words per h row

typedef __attribute__((ext_vector_type(8))) short short8;   // 8 bf16
typedef __attribute__((ext_vector_type(4))) float f32x4;

static __device__ inline unsigned pack_bf16(float a, float b) {
    unsigned ua = __float_as_uint(a), ub = __float_as_uint(b);
    ua = (ua + 0x7fff + ((ua >> 16) & 1)) >> 16;   // RNE
    ub = (ub + 0x7fff + ((ub >> 16) & 1)) >> 16;
    return (ua & 0xffffu) | (ub << 16);
}

// split x = hi + lo, both bf16 (RNE); residual ~2^-18 relative
static __device__ inline void split2(float x, unsigned short* hi, unsigned short* lo) {
    unsigned u = __float_as_uint(x);
    unsigned uh = (u + 0x7fff + ((u >> 16) & 1)) & 0xffff0000u;
    *hi = (unsigned short)(uh >> 16);
    float lo_f = x - __uint_as_float(uh);
    unsigned ul = __float_as_uint(lo_f);
    *lo = (unsigned short)((ul + 0x7fff + ((ul >> 16) & 1)) >> 16);
}

// ---------------- CSR build ----------------

__global__ void count_edges_kernel(const int* __restrict__ dst, int E,
                                   int* __restrict__ cnt) {
    int e = blockIdx.x * 256 + threadIdx.x;
    if (e < E) atomicAdd(&cnt[dst[e]], 1);
}

__global__ __launch_bounds__(1024) void scan_block_kernel(
    const int* __restrict__ cnt, int* __restrict__ incl,
    int* __restrict__ bsum, float* __restrict__ dinv, int N) {
    __shared__ int s[1024];
    int tid = threadIdx.x;
    int i = blockIdx.x * 1024 + tid;
    int v = (i < N) ? cnt[i] : 0;
    if (i < N) dinv[i] = rsqrtf((float)(v + 1));  // +1 self loop
    s[tid] = v;
    __syncthreads();
    for (int off = 1; off < 1024; off <<= 1) {
        int add = (tid >= off) ? s[tid - off] : 0;
        __syncthreads();
        s[tid] += add;
        __syncthreads();
    }
    if (i < N) incl[i] = s[tid];
    if (tid == 1023) bsum[blockIdx.x] = s[1023];
}

__global__ __launch_bounds__(128) void scan_bsum_kernel(int* __restrict__ bsum, int NB) {
    __shared__ int s[128];
    int tid = threadIdx.x;
    int v = (tid < NB) ? bsum[tid] : 0;
    s[tid] = v;
    __syncthreads();
    for (int off = 1; off < 128; off <<= 1) {
        int add = (tid >= off) ? s[tid - off] : 0;
        __syncthreads();
        s[tid] += add;
        __syncthreads();
    }
    if (tid < NB) bsum[tid] = s[tid] - v;  // exclusive
}

__global__ void scan_finalize_kernel(const int* __restrict__ incl,
                                     const int* __restrict__ bsum,
                                     int* __restrict__ rowptr, int N) {
    int i = blockIdx.x * 256 + threadIdx.x;
    if (i < N) rowptr[i + 1] = incl[i] + bsum[i >> 10];
    if (i == 0) rowptr[0] = 0;
}

__global__ void fill_csr_kernel(const int* __restrict__ src, const int* __restrict__ dst,
                                int E, const int* __restrict__ rowptr,
                                int* __restrict__ cur, int* __restrict__ csr_src) {
    int e = blockIdx.x * 256 + threadIdx.x;
    if (e < E) {
        int d = dst[e];
        int pos = atomicAdd(&cur[d], 1);
        csr_src[rowptr[d] + pos] = src[e];
    }
}

// ---------------- W pre-swizzle into B-fragment order ----------------
// frag elem f = ((ks*8 + t)*64 + lane)*8 + j  ->  W[ks*32+(lane>>4)*8+j][t*16+(lane&15)]

__global__ void prep_w_kernel(const float* __restrict__ W,
                              unsigned short* __restrict__ wf_hi,
                              unsigned short* __restrict__ wf_lo) {
    int f = blockIdx.x * 256 + threadIdx.x;   // 0..16383
    int j = f & 7, lane = (f >> 3) & 63, t = (f >> 9) & 7, ks = f >> 12;
    int k = ks * 32 + (lane >> 4) * 8 + j;
    int n = t * 16 + (lane & 15);
    unsigned short hi, lo;
    split2(W[k * 128 + n], &hi, &lo);
    wf_hi[f] = hi;
    wf_lo[f] = lo;
}

// ---------------- MFMA GEMM: H = pack_bf16_perm( X[M,ldx(0:128)] @ W ) ----------------
// 64 rows/block, 256 threads = 4 waves, each wave 16 rows x 128 cols.
// 3-term split-bf16: acc += Ahi*Bhi + Ahi*Blo + Alo*Bhi.

__global__ __launch_bounds__(256) void gemm_mfma_kernel(const float* __restrict__ X, int ldx,
    const unsigned short* __restrict__ wf_hi, const unsigned short* __restrict__ wf_lo,
    unsigned* __restrict__ H, int M) {
    __shared__ unsigned short xs_hi[64 * 128];  // 16 KB, XOR-swizzled
    __shared__ unsigned short xs_lo[64 * 128];  // 16 KB
    int tid = threadIdx.x;
    int row0 = blockIdx.x * 64;

    // stage + split X tile (8 float4 per thread)
#pragma unroll
    for (int i = 0; i < 8; ++i) {
        int idx = tid + i * 256;
        int r = idx >> 5, c4 = (idx & 31) * 4;
        int gr = row0 + r;
        float4 v = make_float4(0.f, 0.f, 0.f, 0.f);
        if (gr < M) v = *(const float4*)(X + (size_t)gr * ldx + c4);
        unsigned short h4[4], l4[4];
        split2(v.x, &h4[0], &l4[0]); split2(v.y, &h4[1], &l4[1]);
        split2(v.z, &h4[2], &l4[2]); split2(v.w, &h4[3], &l4[3]);
        int sidx = r * 128 + (c4 ^ ((r & 7) << 3));   // 8B unit stays intact
        uint2 ph, pl;
        ph.x = (unsigned)h4[0] | ((unsigned)h4[1] << 16);
        ph.y = (unsigned)h4[2] | ((unsigned)h4[3] << 16);
        pl.x = (unsigned)l4[0] | ((unsigned)l4[1] << 16);
        pl.y = (unsigned)l4[2] | ((unsigned)l4[3] << 16);
        *(uint2*)(xs_hi + sidx) = ph;
        *(uint2*)(xs_lo + sidx) = pl;
    }
    __syncthreads();

    int wave = tid >> 6, lane = tid & 63;
    int arow = wave * 16 + (lane & 15);      // A-frag row (within 64-row tile)
    int kgrp = (lane >> 4) * 8;

    f32x4 acc[8];
#pragma unroll
    for (int t = 0; t < 8; ++t) acc[t] = (f32x4){0.f, 0.f, 0.f, 0.f};

#pragma unroll
    for (int ks = 0; ks < 4; ++ks) {
        int k0 = ks * 32 + kgrp;
        int aidx = arow * 128 + (k0 ^ ((arow & 7) << 3));   // 16B-aligned
        short8 a_hi = *(const short8*)(xs_hi + aidx);
        short8 a_lo = *(const short8*)(xs_lo + aidx);
        const unsigned short* bp = wf_hi + ((size_t)(ks * 8) * 64 + lane) * 8;
        const unsigned short* bq = wf_lo + ((size_t)(ks * 8) * 64 + lane) * 8;
#pragma unroll
        for (int t = 0; t < 8; ++t) {
            short8 b_hi = *(const short8*)(bp + t * 512);
            short8 b_lo = *(const short8*)(bq + t * 512);
            acc[t] = __builtin_amdgcn_mfma_f32_16x16x32_bf16(a_hi, b_hi, acc[t], 0, 0, 0);
            acc[t] = __builtin_amdgcn_mfma_f32_16x16x32_bf16(a_hi, b_lo, acc[t], 0, 0, 0);
            acc[t] = __builtin_amdgcn_mfma_f32_16x16x32_bf16(a_lo, b_hi, acc[t], 0, 0, 0);
        }
    }

    // D layout: row=(lane>>4)*4+r, col=lane&15 (per tile t -> feat t*16+col).
    // Pack feats (2j*16+c, (2j+1)*16+c) into word j*16+c.
    int rbase = row0 + wave * 16 + (lane >> 4) * 4;
    int c = lane & 15;
#pragma unroll
    for (int r = 0; r < 4; ++r) {
        int gr = rbase + r;
        if (gr < M) {
#pragma unroll
            for (int j = 0; j < 4; ++j) {
                H[(size_t)gr * HW + j * 16 + c] = pack_bf16(acc[2 * j][r], acc[2 * j + 1][r]);
            }
        }
    }
}

// ---------------- aggregation: one wave per dst node ----------------
// H word l of a row holds feats f0=32*(l>>4)+(l&15) (low), f1=f0+16 (high).

__global__ __launch_bounds__(256) void aggregate_kernel(const unsigned* __restrict__ H,
    const float* __restrict__ dinv, const int* __restrict__ rowptr,
    const int* __restrict__ csr_src, const float* __restrict__ bias,
    float* __restrict__ out, int ldo, int coloff, int N) {
    int node = blockIdx.x * 4 + (threadIdx.x >> 6);
    if (node >= N) return;
    int lane = threadIdx.x & 63;
    int f0 = 32 * (lane >> 4) + (lane & 15), f1 = f0 + 16;

    float di = dinv[node];
    float ax, ay;
    {
        unsigned v = H[(size_t)node * HW + lane];
        ax = __uint_as_float(v << 16) * di;
        ay = __uint_as_float(v & 0xffff0000u) * di;
    }

    int e0 = rowptr[node], e1 = rowptr[node + 1];
    int e = e0;
    for (; e + 3 < e1; e += 4) {
        int s0 = csr_src[e + 0], s1 = csr_src[e + 1];
        int s2 = csr_src[e + 2], s3 = csr_src[e + 3];
        float w0 = dinv[s0], w1 = dinv[s1], w2 = dinv[s2], w3 = dinv[s3];
        unsigned v0 = H[(size_t)s0 * HW + lane];
        unsigned v1 = H[(size_t)s1 * HW + lane];
        unsigned v2 = H[(size_t)s2 * HW + lane];
        unsigned v3 = H[(size_t)s3 * HW + lane];
        ax = fmaf(__uint_as_float(v0 << 16), w0, ax);
        ay = fmaf(__uint_as_float(v0 & 0xffff0000u), w0, ay);
        ax = fmaf(__uint_as_float(v1 << 16), w1, ax);
        ay = fmaf(__uint_as_float(v1 & 0xffff0000u), w1, ay);
        ax = fmaf(__uint_as_float(v2 << 16), w2, ax);
        ay = fmaf(__uint_as_float(v2 & 0xffff0000u), w2, ay);
        ax = fmaf(__uint_as_float(v3 << 16), w3, ax);
        ay = fmaf(__uint_as_float(v3 & 0xffff0000u), w3, ay);
    }
    for (; e < e1; ++e) {
        int s = csr_src[e];
        float ws = dinv[s];
        unsigned v = H[(size_t)s * HW + lane];
        ax = fmaf(__uint_as_float(v << 16), ws, ax);
        ay = fmaf(__uint_as_float(v & 0xffff0000u), ws, ay);
    }

    ax = fmaxf(ax * di + bias[f0], 0.f);
    ay = fmaxf(ay * di + bias[f1], 0.f);
    float* orow = out + (size_t)node * ldo + coloff;
    orow[f0] = ax;
    orow[f1] = ay;
}

// ---------------- launch ----------------

extern "C" void kernel_launch(void* const* d_in, const int* in_sizes, int n_in,
                              void* d_out, int out_size, void* d_ws, size_t ws_size,
                              hipStream_t stream) {
    const float* x  = (const float*)d_in[0];
    const int*   ei = (const int*)d_in[1];   // int32 on device (JAX x64 disabled)
    const float* W1 = (const float*)d_in[2];
    const float* b1 = (const float*)d_in[3];
    const float* W2 = (const float*)d_in[4];
    const float* b2 = (const float*)d_in[5];
    float* out = (float*)d_out;

    const int N = in_sizes[0] / FEAT;   // 100000
    const int E = in_sizes[1] / 2;      // 1600000
    const int* srcs = ei;
    const int* dsts = ei + E;

    const int NB = (N + 1023) / 1024;   // scan blocks (98 <= 128)

    // workspace layout (16B-aligned chunks)
    char* w = (char*)d_ws;
    unsigned* hb  = (unsigned*)w; w += (size_t)N * HW * sizeof(unsigned);  // 25.6 MB
    float* dinv   = (float*)w; w += (size_t)N * sizeof(float);
    int*   cnt    = (int*)w;   w += (size_t)N * sizeof(int);
    int*   cur    = (int*)w;   w += (size_t)N * sizeof(int);
    int*   rowptr = (int*)w;   w += (size_t)(N + 4) * sizeof(int);
    int*   csr    = (int*)w;   w += (size_t)E * sizeof(int);
    int*   incl   = (int*)w;   w += (size_t)N * sizeof(int);
    int*   bsum   = (int*)w;   w += 128 * sizeof(int);
    unsigned short* wf1_hi = (unsigned short*)w; w += 16384 * sizeof(unsigned short);
    unsigned short* wf1_lo = (unsigned short*)w; w += 16384 * sizeof(unsigned short);
    unsigned short* wf2_hi = (unsigned short*)w; w += 16384 * sizeof(unsigned short);
    unsigned short* wf2_lo = (unsigned short*)w; w += 16384 * sizeof(unsigned short);

    hipMemsetAsync(cnt, 0, (size_t)N * sizeof(int), stream);
    hipMemsetAsync(cur, 0, (size_t)N * sizeof(int), stream);

    int eg = (E + 255) / 256;
    int ng = (N + 255) / 256;
    prep_w_kernel<<<64, 256, 0, stream>>>(W1, wf1_hi, wf1_lo);
    prep_w_kernel<<<64, 256, 0, stream>>>(W2, wf2_hi, wf2_lo);
    count_edges_kernel<<<eg, 256, 0, stream>>>(dsts, E, cnt);
    scan_block_kernel<<<NB, 1024, 0, stream>>>(cnt, incl, bsum, dinv, N);
    scan_bsum_kernel<<<1, 128, 0, stream>>>(bsum, NB);
    scan_finalize_kernel<<<ng, 256, 0, stream>>>(incl, bsum, rowptr, N);
    fill_csr_kernel<<<eg, 256, 0, stream>>>(srcs, dsts, E, rowptr, cur, csr);

    int gg = (N + 63) / 64;
    int ag = (N + 3) / 4;
    // layer 1
    gemm_mfma_kernel<<<gg, 256, 0, stream>>>(x, FEAT, wf1_hi, wf1_lo, hb, N);
    aggregate_kernel<<<ag, 256, 0, stream>>>(hb, dinv, rowptr, csr, b1, out, 2 * FEAT, 0, N);
    // layer 2 (input = out cols 0..127, row stride 256)
    gemm_mfma_kernel<<<gg, 256, 0, stream>>>(out, 2 * FEAT, wf2_hi, wf2_lo, hb, N);
    aggregate_kernel<<<ag, 256, 0, stream>>>(hb, dinv, rowptr, csr, b2, out, 2 * FEAT, FEAT, N);
}

// Round 7
// 439.771 us; speedup vs baseline: 2.1518x; 1.1282x over previous
//
#include <hip/hip_runtime.h>
#include <hip/hip_bf16.h>

// GCN 2-layer encoder, N=100000 nodes, C=128 features, E=1.6M edges.
// out[N,256] = concat(relu(gcn(x,W1,b1)), relu(gcn(relu1,W2,b2)))
// gcn: h=XW; agg[d] = sum_{(s,d) in A+I} h[s]*dinv[s]*dinv[d]; +b
// dinv = rsqrt(1 + in_degree(dst))
//
// R1 -> R2: multi-block scan (was 190us single-block, 0.17% occupancy).
// R2 -> R3: h stored packed bf16 (gather 512B->256B rows) + edge loop x4.
// R3 -> R4: GEMM on MFMA via split-bf16 3-term product (fp32-like accuracy).
// R4 -> R6: CSR build restructured: pos-pass (atomic returns slot, coalesced
//           pos[] write) + atomic-free scatter pass (fill_csr was 90us,
//           VALUBusy 0.5% -- atomic->store dependent chain). Aggregate edge
//           batch 4 -> 8 (2.7TB/s = latency-limited, double MLP depth).

#define FEAT 128
#define HW 64   // packed words per h row

typedef __attribute__((ext_vector_type(8))) short short8;   // 8 bf16
typedef __attribute__((ext_vector_type(4))) float f32x4;

static __device__ inline unsigned pack_bf16(float a, float b) {
    unsigned ua = __float_as_uint(a), ub = __float_as_uint(b);
    ua = (ua + 0x7fff + ((ua >> 16) & 1)) >> 16;   // RNE
    ub = (ub + 0x7fff + ((ub >> 16) & 1)) >> 16;
    return (ua & 0xffffu) | (ub << 16);
}

// split x = hi + lo, both bf16 (RNE); residual ~2^-18 relative
static __device__ inline void split2(float x, unsigned short* hi, unsigned short* lo) {
    unsigned u = __float_as_uint(x);
    unsigned uh = (u + 0x7fff + ((u >> 16) & 1)) & 0xffff0000u;
    *hi = (unsigned short)(uh >> 16);
    float lo_f = x - __uint_as_float(uh);
    unsigned ul = __float_as_uint(lo_f);
    *lo = (unsigned short)((ul + 0x7fff + ((ul >> 16) & 1)) >> 16);
}

// ---------------- CSR build ----------------

// Pass 1: per-edge slot via atomic; pos write is coalesced.
__global__ void pos_kernel(const int* __restrict__ dst, int E,
                           int* __restrict__ cnt, int* __restrict__ pos) {
    int e = blockIdx.x * 256 + threadIdx.x;
    if (e < E) pos[e] = atomicAdd(&cnt[dst[e]], 1);
}

__global__ __launch_bounds__(1024) void scan_block_kernel(
    const int* __restrict__ cnt, int* __restrict__ incl,
    int* __restrict__ bsum, float* __restrict__ dinv, int N) {
    __shared__ int s[1024];
    int tid = threadIdx.x;
    int i = blockIdx.x * 1024 + tid;
    int v = (i < N) ? cnt[i] : 0;
    if (i < N) dinv[i] = rsqrtf((float)(v + 1));  // +1 self loop
    s[tid] = v;
    __syncthreads();
    for (int off = 1; off < 1024; off <<= 1) {
        int add = (tid >= off) ? s[tid - off] : 0;
        __syncthreads();
        s[tid] += add;
        __syncthreads();
    }
    if (i < N) incl[i] = s[tid];
    if (tid == 1023) bsum[blockIdx.x] = s[1023];
}

__global__ __launch_bounds__(128) void scan_bsum_kernel(int* __restrict__ bsum, int NB) {
    __shared__ int s[128];
    int tid = threadIdx.x;
    int v = (tid < NB) ? bsum[tid] : 0;
    s[tid] = v;
    __syncthreads();
    for (int off = 1; off < 128; off <<= 1) {
        int add = (tid >= off) ? s[tid - off] : 0;
        __syncthreads();
        s[tid] += add;
        __syncthreads();
    }
    if (tid < NB) bsum[tid] = s[tid] - v;  // exclusive
}

__global__ void scan_finalize_kernel(const int* __restrict__ incl,
                                     const int* __restrict__ bsum,
                                     int* __restrict__ rowptr, int N) {
    int i = blockIdx.x * 256 + threadIdx.x;
    if (i < N) rowptr[i + 1] = incl[i] + bsum[i >> 10];
    if (i == 0) rowptr[0] = 0;
}

// Pass 2: atomic-free scatter. 4 edges/thread via int4, 4 independent
// store chains -> issue-rate bound, not atomic-latency bound.
__global__ void scatter_kernel(const int* __restrict__ src, const int* __restrict__ dst,
                               const int* __restrict__ pos, const int* __restrict__ rowptr,
                               int* __restrict__ csr_src, int E) {
    int t = blockIdx.x * 256 + threadIdx.x;
    int stride = gridDim.x * 256;
    int E4 = E >> 2;
    const int4* s4 = (const int4*)src;
    const int4* d4 = (const int4*)dst;
    const int4* p4 = (const int4*)pos;
    for (int i = t; i < E4; i += stride) {
        int4 d = d4[i], s = s4[i], p = p4[i];
        csr_src[rowptr[d.x] + p.x] = s.x;
        csr_src[rowptr[d.y] + p.y] = s.y;
        csr_src[rowptr[d.z] + p.z] = s.z;
        csr_src[rowptr[d.w] + p.w] = s.w;
    }
    // tail (E not multiple of 4)
    for (int e = E4 * 4 + t; e < E; e += stride) {
        csr_src[rowptr[dst[e]] + pos[e]] = src[e];
    }
}

// ---------------- W pre-swizzle into B-fragment order (both layers) ----------------
// frag elem f = ((ks*8 + t)*64 + lane)*8 + j  ->  W[ks*32+(lane>>4)*8+j][t*16+(lane&15)]

__global__ void prep_w_kernel(const float* __restrict__ W1, const float* __restrict__ W2,
                              unsigned short* __restrict__ wf1_hi, unsigned short* __restrict__ wf1_lo,
                              unsigned short* __restrict__ wf2_hi, unsigned short* __restrict__ wf2_lo) {
    int g = blockIdx.x * 256 + threadIdx.x;   // 0..32767
    int f = g & 16383;
    int j = f & 7, lane = (f >> 3) & 63, t = (f >> 9) & 7, ks = f >> 12;
    int k = ks * 32 + (lane >> 4) * 8 + j;
    int n = t * 16 + (lane & 15);
    unsigned short hi, lo;
    if (g < 16384) {
        split2(W1[k * 128 + n], &hi, &lo);
        wf1_hi[f] = hi; wf1_lo[f] = lo;
    } else {
        split2(W2[k * 128 + n], &hi, &lo);
        wf2_hi[f] = hi; wf2_lo[f] = lo;
    }
}

// ---------------- MFMA GEMM: H = pack_bf16_perm( X[M,ldx(0:128)] @ W ) ----------------
// 64 rows/block, 256 threads = 4 waves, each wave 16 rows x 128 cols.
// 3-term split-bf16: acc += Ahi*Bhi + Ahi*Blo + Alo*Bhi.

__global__ __launch_bounds__(256) void gemm_mfma_kernel(const float* __restrict__ X, int ldx,
    const unsigned short* __restrict__ wf_hi, const unsigned short* __restrict__ wf_lo,
    unsigned* __restrict__ H, int M) {
    __shared__ unsigned short xs_hi[64 * 128];  // 16 KB, XOR-swizzled
    __shared__ unsigned short xs_lo[64 * 128];  // 16 KB
    int tid = threadIdx.x;
    int row0 = blockIdx.x * 64;

    // stage + split X tile (8 float4 per thread)
#pragma unroll
    for (int i = 0; i < 8; ++i) {
        int idx = tid + i * 256;
        int r = idx >> 5, c4 = (idx & 31) * 4;
        int gr = row0 + r;
        float4 v = make_float4(0.f, 0.f, 0.f, 0.f);
        if (gr < M) v = *(const float4*)(X + (size_t)gr * ldx + c4);
        unsigned short h4[4], l4[4];
        split2(v.x, &h4[0], &l4[0]); split2(v.y, &h4[1], &l4[1]);
        split2(v.z, &h4[2], &l4[2]); split2(v.w, &h4[3], &l4[3]);
        int sidx = r * 128 + (c4 ^ ((r & 7) << 3));   // 8B unit stays intact
        uint2 ph, pl;
        ph.x = (unsigned)h4[0] | ((unsigned)h4[1] << 16);
        ph.y = (unsigned)h4[2] | ((unsigned)h4[3] << 16);
        pl.x = (unsigned)l4[0] | ((unsigned)l4[1] << 16);
        pl.y = (unsigned)l4[2] | ((unsigned)l4[3] << 16);
        *(uint2*)(xs_hi + sidx) = ph;
        *(uint2*)(xs_lo + sidx) = pl;
    }
    __syncthreads();

    int wave = tid >> 6, lane = tid & 63;
    int arow = wave * 16 + (lane & 15);      // A-frag row (within 64-row tile)
    int kgrp = (lane >> 4) * 8;

    f32x4 acc[8];
#pragma unroll
    for (int t = 0; t < 8; ++t) acc[t] = (f32x4){0.f, 0.f, 0.f, 0.f};

#pragma unroll
    for (int ks = 0; ks < 4; ++ks) {
        int k0 = ks * 32 + kgrp;
        int aidx = arow * 128 + (k0 ^ ((arow & 7) << 3));   // 16B-aligned
        short8 a_hi = *(const short8*)(xs_hi + aidx);
        short8 a_lo = *(const short8*)(xs_lo + aidx);
        const unsigned short* bp = wf_hi + ((size_t)(ks * 8) * 64 + lane) * 8;
        const unsigned short* bq = wf_lo + ((size_t)(ks * 8) * 64 + lane) * 8;
#pragma unroll
        for (int t = 0; t < 8; ++t) {
            short8 b_hi = *(const short8*)(bp + t * 512);
            short8 b_lo = *(const short8*)(bq + t * 512);
            acc[t] = __builtin_amdgcn_mfma_f32_16x16x32_bf16(a_hi, b_hi, acc[t], 0, 0, 0);
            acc[t] = __builtin_amdgcn_mfma_f32_16x16x32_bf16(a_hi, b_lo, acc[t], 0, 0, 0);
            acc[t] = __builtin_amdgcn_mfma_f32_16x16x32_bf16(a_lo, b_hi, acc[t], 0, 0, 0);
        }
    }

    // D layout: row=(lane>>4)*4+r, col=lane&15 (per tile t -> feat t*16+col).
    // Pack feats (2j*16+c, (2j+1)*16+c) into word j*16+c.
    int rbase = row0 + wave * 16 + (lane >> 4) * 4;
    int c = lane & 15;
#pragma unroll
    for (int r = 0; r < 4; ++r) {
        int gr = rbase + r;
        if (gr < M) {
#pragma unroll
            for (int j = 0; j < 4; ++j) {
                H[(size_t)gr * HW + j * 16 + c] = pack_bf16(acc[2 * j][r], acc[2 * j + 1][r]);
            }
        }
    }
}

// ---------------- aggregation: one wave per dst node, edges batched x8 ----------------
// H word l of a row holds feats f0=32*(l>>4)+(l&15) (low), f1=f0+16 (high).

__global__ __launch_bounds__(256) void aggregate_kernel(const unsigned* __restrict__ H,
    const float* __restrict__ dinv, const int* __restrict__ rowptr,
    const int* __restrict__ csr_src, const float* __restrict__ bias,
    float* __restrict__ out, int ldo, int coloff, int N) {
    int node = blockIdx.x * 4 + (threadIdx.x >> 6);
    if (node >= N) return;
    int lane = threadIdx.x & 63;
    int f0 = 32 * (lane >> 4) + (lane & 15), f1 = f0 + 16;

    float di = dinv[node];
    float ax, ay;
    {
        unsigned v = H[(size_t)node * HW + lane];
        ax = __uint_as_float(v << 16) * di;
        ay = __uint_as_float(v & 0xffff0000u) * di;
    }

    int e0 = rowptr[node], e1 = rowptr[node + 1];
    int e = e0;
    for (; e + 7 < e1; e += 8) {
        int s[8]; float ws[8]; unsigned v[8];
#pragma unroll
        for (int i = 0; i < 8; ++i) s[i] = csr_src[e + i];
#pragma unroll
        for (int i = 0; i < 8; ++i) ws[i] = dinv[s[i]];
#pragma unroll
        for (int i = 0; i < 8; ++i) v[i] = H[(size_t)s[i] * HW + lane];
#pragma unroll
        for (int i = 0; i < 8; ++i) {
            ax = fmaf(__uint_as_float(v[i] << 16), ws[i], ax);
            ay = fmaf(__uint_as_float(v[i] & 0xffff0000u), ws[i], ay);
        }
    }
    for (; e + 3 < e1; e += 4) {
        int s[4]; float ws[4]; unsigned v[4];
#pragma unroll
        for (int i = 0; i < 4; ++i) s[i] = csr_src[e + i];
#pragma unroll
        for (int i = 0; i < 4; ++i) ws[i] = dinv[s[i]];
#pragma unroll
        for (int i = 0; i < 4; ++i) v[i] = H[(size_t)s[i] * HW + lane];
#pragma unroll
        for (int i = 0; i < 4; ++i) {
            ax = fmaf(__uint_as_float(v[i] << 16), ws[i], ax);
            ay = fmaf(__uint_as_float(v[i] & 0xffff0000u), ws[i], ay);
        }
    }
    for (; e < e1; ++e) {
        int s = csr_src[e];
        float ws = dinv[s];
        unsigned v = H[(size_t)s * HW + lane];
        ax = fmaf(__uint_as_float(v << 16), ws, ax);
        ay = fmaf(__uint_as_float(v & 0xffff0000u), ws, ay);
    }

    ax = fmaxf(ax * di + bias[f0], 0.f);
    ay = fmaxf(ay * di + bias[f1], 0.f);
    float* orow = out + (size_t)node * ldo + coloff;
    orow[f0] = ax;
    orow[f1] = ay;
}

// ---------------- launch ----------------

extern "C" void kernel_launch(void* const* d_in, const int* in_sizes, int n_in,
                              void* d_out, int out_size, void* d_ws, size_t ws_size,
                              hipStream_t stream) {
    const float* x  = (const float*)d_in[0];
    const int*   ei = (const int*)d_in[1];   // int32 on device (JAX x64 disabled)
    const float* W1 = (const float*)d_in[2];
    const float* b1 = (const float*)d_in[3];
    const float* W2 = (const float*)d_in[4];
    const float* b2 = (const float*)d_in[5];
    float* out = (float*)d_out;

    const int N = in_sizes[0] / FEAT;   // 100000
    const int E = in_sizes[1] / 2;      // 1600000
    const int* srcs = ei;
    const int* dsts = ei + E;

    const int NB = (N + 1023) / 1024;   // scan blocks (98 <= 128)

    // workspace layout (16B-aligned chunks)
    char* w = (char*)d_ws;
    unsigned* hb  = (unsigned*)w; w += (size_t)N * HW * sizeof(unsigned);  // 25.6 MB
    float* dinv   = (float*)w; w += (size_t)N * sizeof(float);
    int*   cnt    = (int*)w;   w += (size_t)N * sizeof(int);
    int*   rowptr = (int*)w;   w += (size_t)(N + 4) * sizeof(int);
    int*   csr    = (int*)w;   w += (size_t)E * sizeof(int);
    int*   pos    = (int*)w;   w += (size_t)E * sizeof(int);
    int*   incl   = (int*)w;   w += (size_t)N * sizeof(int);
    int*   bsum   = (int*)w;   w += 128 * sizeof(int);
    unsigned short* wf1_hi = (unsigned short*)w; w += 16384 * sizeof(unsigned short);
    unsigned short* wf1_lo = (unsigned short*)w; w += 16384 * sizeof(unsigned short);
    unsigned short* wf2_hi = (unsigned short*)w; w += 16384 * sizeof(unsigned short);
    unsigned short* wf2_lo = (unsigned short*)w; w += 16384 * sizeof(unsigned short);

    hipMemsetAsync(cnt, 0, (size_t)N * sizeof(int), stream);

    int eg = (E + 255) / 256;
    int ng = (N + 255) / 256;
    prep_w_kernel<<<128, 256, 0, stream>>>(W1, W2, wf1_hi, wf1_lo, wf2_hi, wf2_lo);
    pos_kernel<<<eg, 256, 0, stream>>>(dsts, E, cnt, pos);
    scan_block_kernel<<<NB, 1024, 0, stream>>>(cnt, incl, bsum, dinv, N);
    scan_bsum_kernel<<<1, 128, 0, stream>>>(bsum, NB);
    scan_finalize_kernel<<<ng, 256, 0, stream>>>(incl, bsum, rowptr, N);
    scatter_kernel<<<1024, 256, 0, stream>>>(srcs, dsts, pos, rowptr, csr, E);

    int gg = (N + 63) / 64;
    int ag = (N + 3) / 4;
    // layer 1
    gemm_mfma_kernel<<<gg, 256, 0, stream>>>(x, FEAT, wf1_hi, wf1_lo, hb, N);
    aggregate_kernel<<<ag, 256, 0, stream>>>(hb, dinv, rowptr, csr, b1, out, 2 * FEAT, 0, N);
    // layer 2 (input = out cols 0..127, row stride 256)
    gemm_mfma_kernel<<<gg, 256, 0, stream>>>(out, 2 * FEAT, wf2_hi, wf2_lo, hb, N);
    aggregate_kernel<<<ag, 256, 0, stream>>>(hb, dinv, rowptr, csr, b2, out, 2 * FEAT, FEAT, N);
}